// Round 1
// baseline (9117.500 us; speedup 1.0000x reference)
//
#include <hip/hip_runtime.h>

// CNF: B=262144 samples, D=8, H=64.
// outputs: dz_dt (B*8) | dlogp_z_dt (B) | g (B), all f32, concat flat.

#define BATCH 262144
#define DD 8
#define HH 64

__device__ __forceinline__ float tanh_fast(float x) {
    // tanh(x) = 1 - 2/(exp(2x)+1), exp via exp2. Handles +-inf saturation.
    float e = __builtin_amdgcn_exp2f(x * 2.8853900817779268f); // 2*log2(e)
    return 1.0f - 2.0f * __builtin_amdgcn_rcpf(e + 1.0f);
}

__global__ void __launch_bounds__(256, 1) cnf_kernel(
    const float* __restrict__ tp, const float* __restrict__ zp,
    const float* __restrict__ w1_0, const float* __restrict__ b1_0,
    const float* __restrict__ w1_1, const float* __restrict__ b1_1,
    const float* __restrict__ w1_2, const float* __restrict__ b1_2,
    const float* __restrict__ w1_o, const float* __restrict__ b1_o,
    const float* __restrict__ w2_0, const float* __restrict__ b2_0,
    const float* __restrict__ w2_1, const float* __restrict__ b2_1,
    const float* __restrict__ w2_2, const float* __restrict__ b2_2,
    const float* __restrict__ w2_o, const float* __restrict__ b2_o,
    float* __restrict__ out)
{
    const int idx = blockIdx.x * blockDim.x + threadIdx.x;
    const float tt = tp[0];

    float4 z0 = *reinterpret_cast<const float4*>(zp + (size_t)idx * 8);
    float4 z1 = *reinterpret_cast<const float4*>(zp + (size_t)idx * 8 + 4);
    float z[DD] = {z0.x, z0.y, z0.z, z0.w, z1.x, z1.y, z1.z, z1.w};

    float t1v[HH], t2v[HH], t3v[HH];
    float xa[HH], xb[HH];

    // ---- net1 forward ----
    // layer 0: s = [t, z] @ w1_0 + b1_0 ; tanh
    #pragma unroll
    for (int j = 0; j < HH; ++j) {
        float u = b1_0[j] + tt * w1_0[j];   // row 0 = t row
        #pragma unroll
        for (int d = 0; d < DD; ++d) u = fmaf(z[d], w1_0[(d + 1) * HH + j], u);
        float e = tanh_fast(u);
        xa[j] = e;
        t1v[j] = 1.0f - e * e;
    }
    // layer 1
    #pragma unroll
    for (int j = 0; j < HH; ++j) {
        float u = b1_1[j];
        #pragma unroll
        for (int i = 0; i < HH; ++i) u = fmaf(xa[i], w1_1[i * HH + j], u);
        float e = tanh_fast(u);
        xb[j] = e;
        t2v[j] = 1.0f - e * e;
    }
    // layer 2 + streamed output layer (dz_dt)
    float acc[DD];
    #pragma unroll
    for (int d = 0; d < DD; ++d) acc[d] = b1_o[d];
    #pragma unroll
    for (int j = 0; j < HH; ++j) {
        float u = b1_2[j];
        #pragma unroll
        for (int i = 0; i < HH; ++i) u = fmaf(xb[i], w1_2[i * HH + j], u);
        float e = tanh_fast(u);
        t3v[j] = 1.0f - e * e;
        #pragma unroll
        for (int d = 0; d < DD; ++d) acc[d] = fmaf(e, w1_o[j * DD + d], acc[d]);
    }
    // store dz_dt
    float4 o0 = {acc[0], acc[1], acc[2], acc[3]};
    float4 o1 = {acc[4], acc[5], acc[6], acc[7]};
    *reinterpret_cast<float4*>(out + (size_t)idx * 8) = o0;
    *reinterpret_cast<float4*>(out + (size_t)idx * 8 + 4) = o1;

    // ---- exact trace via 8 JVPs, fused reverse direction per tangent ----
    // outdot_d = sum_k xd1[k] * q[k]
    //   xd1[k] = t1[k] * w1_0[(1+d),k]
    //   q[k]   = sum_i W1[k,i] * sB[i],  sB[i] = t2[i] * sum_j W2[i,j] * sA[j]
    //   sA[j]  = t3[j] * w1_o[j,d]
    float trace = 0.0f;
    float sA[HH], sB[HH];
    #pragma unroll 1
    for (int d = 0; d < DD; ++d) {
        #pragma unroll
        for (int j = 0; j < HH; ++j) sA[j] = t3v[j] * w1_o[j * DD + d];
        #pragma unroll
        for (int i = 0; i < HH; ++i) {
            float r = 0.0f;
            #pragma unroll
            for (int j = 0; j < HH; ++j) r = fmaf(w1_2[i * HH + j], sA[j], r);
            sB[i] = t2v[i] * r;
        }
        #pragma unroll
        for (int k = 0; k < HH; ++k) {
            float q = 0.0f;
            #pragma unroll
            for (int i = 0; i < HH; ++i) q = fmaf(w1_1[k * HH + i], sB[i], q);
            trace = fmaf(t1v[k] * w1_0[(d + 1) * HH + k], q, trace);
        }
    }

    // ---- net2 forward (reuse xa/xb; t arrays dead) ----
    #pragma unroll
    for (int j = 0; j < HH; ++j) {
        float u = b2_0[j] + tt * w2_0[j];
        #pragma unroll
        for (int d = 0; d < DD; ++d) u = fmaf(z[d], w2_0[(d + 1) * HH + j], u);
        xa[j] = tanh_fast(u);
    }
    #pragma unroll
    for (int j = 0; j < HH; ++j) {
        float u = b2_1[j];
        #pragma unroll
        for (int i = 0; i < HH; ++i) u = fmaf(xa[i], w2_1[i * HH + j], u);
        xb[j] = tanh_fast(u);
    }
    float g = b2_o[0];
    #pragma unroll
    for (int j = 0; j < HH; ++j) {
        float u = b2_2[j];
        #pragma unroll
        for (int i = 0; i < HH; ++i) u = fmaf(xb[i], w2_2[i * HH + j], u);
        g = fmaf(tanh_fast(u), w2_o[j], g);
    }

    out[(size_t)BATCH * 8 + idx] = g - trace;  // dlogp_z_dt
    out[(size_t)BATCH * 9 + idx] = g;          // g
}

extern "C" void kernel_launch(void* const* d_in, const int* in_sizes, int n_in,
                              void* d_out, int out_size, void* d_ws, size_t ws_size,
                              hipStream_t stream) {
    const float* tp   = (const float*)d_in[0];
    const float* zp   = (const float*)d_in[1];
    // d_in[2] = logp_z (unused by the reference outputs)
    const float* w1_0 = (const float*)d_in[3];
    const float* b1_0 = (const float*)d_in[4];
    const float* w1_1 = (const float*)d_in[5];
    const float* b1_1 = (const float*)d_in[6];
    const float* w1_2 = (const float*)d_in[7];
    const float* b1_2 = (const float*)d_in[8];
    const float* w1_o = (const float*)d_in[9];
    const float* b1_o = (const float*)d_in[10];
    const float* w2_0 = (const float*)d_in[11];
    const float* b2_0 = (const float*)d_in[12];
    const float* w2_1 = (const float*)d_in[13];
    const float* b2_1 = (const float*)d_in[14];
    const float* w2_2 = (const float*)d_in[15];
    const float* b2_2 = (const float*)d_in[16];
    const float* w2_o = (const float*)d_in[17];
    const float* b2_o = (const float*)d_in[18];
    float* out = (float*)d_out;

    dim3 grid(BATCH / 256), block(256);
    hipLaunchKernelGGL(cnf_kernel, grid, block, 0, stream,
                       tp, zp, w1_0, b1_0, w1_1, b1_1, w1_2, b1_2, w1_o, b1_o,
                       w2_0, b2_0, w2_1, b2_1, w2_2, b2_2, w2_o, b2_o, out);
}

// Round 2
// 4569.502 us; speedup vs baseline: 1.9953x; 1.9953x over previous
//
#include <hip/hip_runtime.h>
#include <hip/hip_fp16.h>

// CNF: B=262144 samples, D=8, H=64.
// outputs: dz_dt (B*8) | dlogp_z_dt (B) | g (B), all f32, concat flat.

#define BATCH 262144
#define DD 8
#define HH 64

__device__ __forceinline__ float tanh_fast(float x) {
    // tanh(x) = 1 - 2/(exp(2x)+1), exp via exp2. Handles +-inf saturation.
    float e = __builtin_amdgcn_exp2f(x * 2.8853900817779268f); // 2*log2(e)
    return 1.0f - 2.0f * __builtin_amdgcn_rcpf(e + 1.0f);
}

// A[d][i][j] = w1_2[i][j] * w1_o[j][d]  (sample-independent; 8*64*64 f32 = 128 KB)
__global__ void __launch_bounds__(256) setupA(const float* __restrict__ w1_2,
                                              const float* __restrict__ w1_o,
                                              float* __restrict__ A) {
    int t = blockIdx.x * 256 + threadIdx.x;  // 0..32767
    int j = t & 63;
    int i = (t >> 6) & 63;
    int d = t >> 12;
    A[t] = w1_2[i * 64 + j] * w1_o[j * 8 + d];
}

__global__ void __launch_bounds__(256, 2) cnf_main(
    const float* __restrict__ tp, const float* __restrict__ zp,
    const float* __restrict__ w1_0, const float* __restrict__ b1_0,
    const float* __restrict__ w1_1, const float* __restrict__ b1_1,
    const float* __restrict__ w1_2, const float* __restrict__ b1_2,
    const float* __restrict__ w1_o, const float* __restrict__ b1_o,
    const float* __restrict__ w2_0, const float* __restrict__ b2_0,
    const float* __restrict__ w2_1, const float* __restrict__ b2_1,
    const float* __restrict__ w2_2, const float* __restrict__ b2_2,
    const float* __restrict__ w2_o, const float* __restrict__ b2_o,
    const float* __restrict__ A,
    float* __restrict__ out)
{
    const int idx = blockIdx.x * blockDim.x + threadIdx.x;
    const float tt = tp[0];

    float4 z0 = *reinterpret_cast<const float4*>(zp + (size_t)idx * 8);
    float4 z1 = *reinterpret_cast<const float4*>(zp + (size_t)idx * 8 + 4);
    float z[DD] = {z0.x, z0.y, z0.z, z0.w, z1.x, z1.y, z1.z, z1.w};

    // ---- net1 L0: xa = tanh([t,z] @ w1_0 + b1_0) ----
    float xa[HH];
    #pragma unroll
    for (int j = 0; j < HH; ++j) {
        float u = b1_0[j] + tt * w1_0[j];
        #pragma unroll
        for (int d = 0; d < DD; ++d) u = fmaf(z[d], w1_0[(d + 1) * HH + j], u);
        xa[j] = tanh_fast(u);
    }

    // ---- net1 L1: xb = tanh(xa @ w1_1 + b1_1) ----
    float xb[HH];
    #pragma unroll
    for (int j = 0; j < HH; ++j) {
        float u0 = b1_1[j], u1 = 0.0f;
        #pragma unroll
        for (int i = 0; i < HH; i += 2) {
            u0 = fmaf(xa[i],     w1_1[i * HH + j],       u0);
            u1 = fmaf(xa[i + 1], w1_1[(i + 1) * HH + j], u1);
        }
        xb[j] = tanh_fast(u0 + u1);
    }

    // pack t1 = 1 - xa^2 as f16 pairs; xa dies here
    __half2 t1h[HH / 2];
    #pragma unroll
    for (int k = 0; k < HH; k += 2) {
        t1h[k >> 1] = __floats2half2_rn(fmaf(-xa[k], xa[k], 1.0f),
                                        fmaf(-xa[k + 1], xa[k + 1], 1.0f));
    }

    // ---- net1 L2 + output layer streamed; t3 = 1 - x3^2 kept in f32 ----
    float t3[HH];
    float acc[DD];
    #pragma unroll
    for (int d = 0; d < DD; ++d) acc[d] = b1_o[d];
    #pragma unroll
    for (int j = 0; j < HH; ++j) {
        float u0 = b1_2[j], u1 = 0.0f;
        #pragma unroll
        for (int i = 0; i < HH; i += 2) {
            u0 = fmaf(xb[i],     w1_2[i * HH + j],       u0);
            u1 = fmaf(xb[i + 1], w1_2[(i + 1) * HH + j], u1);
        }
        float e = tanh_fast(u0 + u1);
        t3[j] = fmaf(-e, e, 1.0f);
        #pragma unroll
        for (int d = 0; d < DD; ++d) acc[d] = fmaf(e, w1_o[j * DD + d], acc[d]);
    }

    // pack t2 = 1 - xb^2 as f16 pairs; xb dies here
    __half2 t2h[HH / 2];
    #pragma unroll
    for (int k = 0; k < HH; k += 2) {
        t2h[k >> 1] = __floats2half2_rn(fmaf(-xb[k], xb[k], 1.0f),
                                        fmaf(-xb[k + 1], xb[k + 1], 1.0f));
    }

    // store dz_dt
    float4 o0 = {acc[0], acc[1], acc[2], acc[3]};
    float4 o1 = {acc[4], acc[5], acc[6], acc[7]};
    *reinterpret_cast<float4*>(out + (size_t)idx * 8) = o0;
    *reinterpret_cast<float4*>(out + (size_t)idx * 8 + 4) = o1;

    // ---- exact trace: 8 reverse sweeps; sA folded into A_d ----
    // live arrays: t1h(32) t2h(32) t3(64) sB(64)
    float trace = 0.0f;
    #pragma unroll 1
    for (int d = 0; d < DD; ++d) {
        const float* __restrict__ Ad = A + d * (HH * HH);
        const float* __restrict__ W0zd = w1_0 + (d + 1) * HH;
        float sB[HH];
        #pragma unroll
        for (int i = 0; i < HH; ++i) {
            float r0 = 0.0f, r1 = 0.0f;
            #pragma unroll
            for (int j = 0; j < HH; j += 2) {
                r0 = fmaf(Ad[i * HH + j],     t3[j],     r0);
                r1 = fmaf(Ad[i * HH + j + 1], t3[j + 1], r1);
            }
            float t2i = (i & 1) ? __high2float(t2h[i >> 1]) : __low2float(t2h[i >> 1]);
            sB[i] = t2i * (r0 + r1);
        }
        #pragma unroll
        for (int k = 0; k < HH; ++k) {
            float q0 = 0.0f, q1 = 0.0f;
            #pragma unroll
            for (int i = 0; i < HH; i += 2) {
                q0 = fmaf(w1_1[k * HH + i],     sB[i],     q0);
                q1 = fmaf(w1_1[k * HH + i + 1], sB[i + 1], q1);
            }
            float t1k = (k & 1) ? __high2float(t1h[k >> 1]) : __low2float(t1h[k >> 1]);
            trace = fmaf(t1k * W0zd[k], q0 + q1, trace);
        }
    }

    // ---- net2 forward (z reloaded; trace arrays dead) ----
    z0 = *reinterpret_cast<const float4*>(zp + (size_t)idx * 8);
    z1 = *reinterpret_cast<const float4*>(zp + (size_t)idx * 8 + 4);
    float z2[DD] = {z0.x, z0.y, z0.z, z0.w, z1.x, z1.y, z1.z, z1.w};

    float ya[HH];
    #pragma unroll
    for (int j = 0; j < HH; ++j) {
        float u = b2_0[j] + tt * w2_0[j];
        #pragma unroll
        for (int d = 0; d < DD; ++d) u = fmaf(z2[d], w2_0[(d + 1) * HH + j], u);
        ya[j] = tanh_fast(u);
    }
    float yb[HH];
    #pragma unroll
    for (int j = 0; j < HH; ++j) {
        float u0 = b2_1[j], u1 = 0.0f;
        #pragma unroll
        for (int i = 0; i < HH; i += 2) {
            u0 = fmaf(ya[i],     w2_1[i * HH + j],       u0);
            u1 = fmaf(ya[i + 1], w2_1[(i + 1) * HH + j], u1);
        }
        yb[j] = tanh_fast(u0 + u1);
    }
    float g = b2_o[0];
    #pragma unroll
    for (int j = 0; j < HH; ++j) {
        float u0 = b2_2[j], u1 = 0.0f;
        #pragma unroll
        for (int i = 0; i < HH; i += 2) {
            u0 = fmaf(yb[i],     w2_2[i * HH + j],       u0);
            u1 = fmaf(yb[i + 1], w2_2[(i + 1) * HH + j], u1);
        }
        g = fmaf(tanh_fast(u0 + u1), w2_o[j], g);
    }

    out[(size_t)BATCH * 8 + idx] = g - trace;  // dlogp_z_dt
    out[(size_t)BATCH * 9 + idx] = g;          // g
}

extern "C" void kernel_launch(void* const* d_in, const int* in_sizes, int n_in,
                              void* d_out, int out_size, void* d_ws, size_t ws_size,
                              hipStream_t stream) {
    const float* tp   = (const float*)d_in[0];
    const float* zp   = (const float*)d_in[1];
    // d_in[2] = logp_z (unused)
    const float* w1_0 = (const float*)d_in[3];
    const float* b1_0 = (const float*)d_in[4];
    const float* w1_1 = (const float*)d_in[5];
    const float* b1_1 = (const float*)d_in[6];
    const float* w1_2 = (const float*)d_in[7];
    const float* b1_2 = (const float*)d_in[8];
    const float* w1_o = (const float*)d_in[9];
    const float* b1_o = (const float*)d_in[10];
    const float* w2_0 = (const float*)d_in[11];
    const float* b2_0 = (const float*)d_in[12];
    const float* w2_1 = (const float*)d_in[13];
    const float* b2_1 = (const float*)d_in[14];
    const float* w2_2 = (const float*)d_in[15];
    const float* b2_2 = (const float*)d_in[16];
    const float* w2_o = (const float*)d_in[17];
    const float* b2_o = (const float*)d_in[18];
    float* out = (float*)d_out;
    float* A   = (float*)d_ws;   // 8*64*64 f32 = 128 KB

    hipLaunchKernelGGL(setupA, dim3(128), dim3(256), 0, stream, w1_2, w1_o, A);
    hipLaunchKernelGGL(cnf_main, dim3(BATCH / 256), dim3(256), 0, stream,
                       tp, zp, w1_0, b1_0, w1_1, b1_1, w1_2, b1_2, w1_o, b1_o,
                       w2_0, b2_0, w2_1, b2_1, w2_2, b2_2, w2_o, b2_o, A, out);
}